// Round 1
// baseline (48.033 us; speedup 1.0000x reference)
//
#include <hip/hip_runtime.h>

#define BT 128
#define NTHREADS 256

typedef __attribute__((ext_vector_type(8))) __bf16 bf16x8;
typedef __attribute__((ext_vector_type(4))) __bf16 bf16x4;
typedef __attribute__((ext_vector_type(4))) float f32x4;

__device__ __forceinline__ __bf16 f2bf(float f) { return (__bf16)f; }

__global__ __launch_bounds__(NTHREADS, 2)
void ncf_fused(const int* __restrict__ user_ids, const int* __restrict__ movie_ids,
               const int* __restrict__ genre_ids, const int* __restrict__ offsets,
               const float* __restrict__ user_mem_w, const float* __restrict__ movie_mem_w,
               const float* __restrict__ ue_gmf, const float* __restrict__ me_gmf,
               const float* __restrict__ ge_gmf,
               const float* __restrict__ ue_mlp, const float* __restrict__ me_mlp,
               const float* __restrict__ ge_mlp,
               const float* __restrict__ w1, const float* __restrict__ b1,
               const float* __restrict__ w2, const float* __restrict__ b2,
               const float* __restrict__ w_out, const float* __restrict__ b_out,
               float* __restrict__ out, int Btot, int totG)
{
    // X: [128][192+8] bf16 (pad keeps 16B row alignment, breaks bank alignment)
    __shared__ __bf16 Xs[BT * 200];
    // H: [128][64+8] bf16
    __shared__ __bf16 Hs[BT * 72];
    __shared__ float partial[BT];

    const int tid = threadIdx.x;
    const int e0 = blockIdx.x * BT;

    // ================= Phase 1: gather + GMF partial =================
    {
        const int c = tid & 7;               // 8 threads per element
        for (int p = 0; p < 4; ++p) {
            const int e = p * 32 + (tid >> 3);   // 0..127
            const int gidx = min(e0 + e, Btot - 1);
            const int u  = user_ids[gidx];
            const int mv = movie_ids[gidx];

            // --- ue_mlp: 96 f32 -> Xs[e][0..95], this thread covers c*12..c*12+11
            {
                const float4* src = (const float4*)(ue_mlp + (size_t)u * 96 + c * 12);
                #pragma unroll
                for (int q = 0; q < 3; ++q) {
                    float4 v = src[q];
                    bf16x4 b; b[0]=f2bf(v.x); b[1]=f2bf(v.y); b[2]=f2bf(v.z); b[3]=f2bf(v.w);
                    *(bf16x4*)&Xs[e * 200 + c * 12 + q * 4] = b;
                }
            }
            // --- me_mlp: 64 f32 -> Xs[e][96..159], thread covers 96 + c*8 ..
            {
                const float4* src = (const float4*)(me_mlp + (size_t)mv * 64 + c * 8);
                #pragma unroll
                for (int q = 0; q < 2; ++q) {
                    float4 v = src[q];
                    bf16x4 b; b[0]=f2bf(v.x); b[1]=f2bf(v.y); b[2]=f2bf(v.z); b[3]=f2bf(v.w);
                    *(bf16x4*)&Xs[e * 200 + 96 + c * 8 + q * 4] = b;
                }
            }
            const int gs  = offsets[gidx];
            const int gend = (gidx + 1 < Btot) ? offsets[gidx + 1] : totG;
            const int cnt = gend - gs;
            const float inv = 1.0f / (float)(cnt > 0 ? cnt : 1);
            // --- genre-mean mlp: 32 f32 -> Xs[e][160..191], thread covers 160 + c*4
            {
                float ax = 0.f, ay = 0.f, az = 0.f, aw = 0.f;
                for (int i = gs; i < gend; ++i) {
                    const int g = genre_ids[i];
                    float4 v = *(const float4*)(ge_mlp + (size_t)g * 32 + c * 4);
                    ax += v.x; ay += v.y; az += v.z; aw += v.w;
                }
                bf16x4 b; b[0]=f2bf(ax*inv); b[1]=f2bf(ay*inv); b[2]=f2bf(az*inv); b[3]=f2bf(aw*inv);
                *(bf16x4*)&Xs[e * 200 + 160 + c * 4] = b;
            }
            // --- GMF: partial[e] = sum_d ue_gmf[u][d]*mg[d]*w_out[d] + mems + b_out
            {
                float s = 0.f;
                #pragma unroll
                for (int kk = 0; kk < 12; ++kk) {
                    const int d = c + 8 * kk;   // stride-8 over 0..95
                    const float ug = ue_gmf[(size_t)u * 96 + d];
                    float mg;
                    if (d < 64) {
                        mg = me_gmf[(size_t)mv * 64 + d];
                    } else {
                        mg = 0.f;
                        for (int i = gs; i < gend; ++i)
                            mg += ge_gmf[(size_t)genre_ids[i] * 32 + (d - 64)];
                        mg *= inv;
                    }
                    s += ug * mg * w_out[d];
                }
                s += __shfl_xor(s, 1);
                s += __shfl_xor(s, 2);
                s += __shfl_xor(s, 4);
                if (c == 0)
                    partial[e] = s + user_mem_w[u] + movie_mem_w[mv] + b_out[0];
            }
        }
    }
    __syncthreads();

    // ================= Phase 2: GEMM1  X[128x192] @ W1^T[192x64] -> H =================
    const int lane = tid & 63;
    const int wid  = tid >> 6;      // 4 waves, each owns 32 rows
    const int lr   = lane & 15;
    const int lg   = lane >> 4;

    f32x4 acc1[2][4] = {};
    #pragma unroll
    for (int kt = 0; kt < 6; ++kt) {
        bf16x8 bw[4];
        #pragma unroll
        for (int nt = 0; nt < 4; ++nt) {
            const float* wp = w1 + (size_t)(nt * 16 + lr) * 192 + kt * 32 + lg * 8;
            float4 wa = *(const float4*)wp;
            float4 wb = *(const float4*)(wp + 4);
            bf16x8 t;
            t[0]=f2bf(wa.x); t[1]=f2bf(wa.y); t[2]=f2bf(wa.z); t[3]=f2bf(wa.w);
            t[4]=f2bf(wb.x); t[5]=f2bf(wb.y); t[6]=f2bf(wb.z); t[7]=f2bf(wb.w);
            bw[nt] = t;
        }
        #pragma unroll
        for (int mt = 0; mt < 2; ++mt) {
            bf16x8 av = *(const bf16x8*)&Xs[(wid * 32 + mt * 16 + lr) * 200 + kt * 32 + lg * 8];
            #pragma unroll
            for (int nt = 0; nt < 4; ++nt)
                acc1[mt][nt] = __builtin_amdgcn_mfma_f32_16x16x32_bf16(av, bw[nt], acc1[mt][nt], 0, 0, 0);
        }
    }
    // bias + relu -> Hs (D layout: row = lg*4+r, col = lr)
    #pragma unroll
    for (int nt = 0; nt < 4; ++nt) {
        const float bv = b1[nt * 16 + lr];
        #pragma unroll
        for (int mt = 0; mt < 2; ++mt) {
            #pragma unroll
            for (int r = 0; r < 4; ++r) {
                float v = acc1[mt][nt][r] + bv;
                v = v > 0.f ? v : 0.f;
                Hs[(wid * 32 + mt * 16 + lg * 4 + r) * 72 + nt * 16 + lr] = f2bf(v);
            }
        }
    }
    __syncthreads();

    // ================= Phase 3: GEMM2  H[128x64] @ W2^T[64x96], fuse epilogue =================
    f32x4 acc2[2][6] = {};
    #pragma unroll
    for (int kt = 0; kt < 2; ++kt) {
        bf16x8 bw[6];
        #pragma unroll
        for (int nt = 0; nt < 6; ++nt) {
            const float* wp = w2 + (size_t)(nt * 16 + lr) * 64 + kt * 32 + lg * 8;
            float4 wa = *(const float4*)wp;
            float4 wb = *(const float4*)(wp + 4);
            bf16x8 t;
            t[0]=f2bf(wa.x); t[1]=f2bf(wa.y); t[2]=f2bf(wa.z); t[3]=f2bf(wa.w);
            t[4]=f2bf(wb.x); t[5]=f2bf(wb.y); t[6]=f2bf(wb.z); t[7]=f2bf(wb.w);
            bw[nt] = t;
        }
        #pragma unroll
        for (int mt = 0; mt < 2; ++mt) {
            bf16x8 av = *(const bf16x8*)&Hs[(wid * 32 + mt * 16 + lr) * 72 + kt * 32 + lg * 8];
            #pragma unroll
            for (int nt = 0; nt < 6; ++nt)
                acc2[mt][nt] = __builtin_amdgcn_mfma_f32_16x16x32_bf16(av, bw[nt], acc2[mt][nt], 0, 0, 0);
        }
    }
    // bias + relu + dot with w_out[96:192], reduce over the 16 cols, add partial
    #pragma unroll
    for (int mt = 0; mt < 2; ++mt) {
        float s0 = 0.f, s1 = 0.f, s2 = 0.f, s3 = 0.f;
        #pragma unroll
        for (int nt = 0; nt < 6; ++nt) {
            const int col = nt * 16 + lr;
            const float b2v = b2[col];
            const float wo  = w_out[96 + col];
            float v;
            v = acc2[mt][nt][0] + b2v; v = v > 0.f ? v : 0.f; s0 += v * wo;
            v = acc2[mt][nt][1] + b2v; v = v > 0.f ? v : 0.f; s1 += v * wo;
            v = acc2[mt][nt][2] + b2v; v = v > 0.f ? v : 0.f; s2 += v * wo;
            v = acc2[mt][nt][3] + b2v; v = v > 0.f ? v : 0.f; s3 += v * wo;
        }
        #pragma unroll
        for (int mask = 1; mask <= 8; mask <<= 1) {
            s0 += __shfl_xor(s0, mask);
            s1 += __shfl_xor(s1, mask);
            s2 += __shfl_xor(s2, mask);
            s3 += __shfl_xor(s3, mask);
        }
        if (lr == 0) {
            const int rowb = wid * 32 + mt * 16 + lg * 4;
            if (e0 + rowb + 3 < Btot || e0 + rowb < Btot) {
                if (e0 + rowb + 0 < Btot) out[e0 + rowb + 0] = partial[rowb + 0] + s0;
                if (e0 + rowb + 1 < Btot) out[e0 + rowb + 1] = partial[rowb + 1] + s1;
                if (e0 + rowb + 2 < Btot) out[e0 + rowb + 2] = partial[rowb + 2] + s2;
                if (e0 + rowb + 3 < Btot) out[e0 + rowb + 3] = partial[rowb + 3] + s3;
            }
        }
    }
}

extern "C" void kernel_launch(void* const* d_in, const int* in_sizes, int n_in,
                              void* d_out, int out_size, void* d_ws, size_t ws_size,
                              hipStream_t stream) {
    const int*   user_ids    = (const int*)d_in[0];
    const int*   movie_ids   = (const int*)d_in[1];
    const int*   genre_ids   = (const int*)d_in[2];
    const int*   offsets     = (const int*)d_in[3];
    const float* user_mem_w  = (const float*)d_in[4];
    const float* movie_mem_w = (const float*)d_in[5];
    const float* ue_gmf      = (const float*)d_in[6];
    const float* me_gmf      = (const float*)d_in[7];
    const float* ge_gmf      = (const float*)d_in[8];
    const float* ue_mlp      = (const float*)d_in[9];
    const float* me_mlp      = (const float*)d_in[10];
    const float* ge_mlp      = (const float*)d_in[11];
    const float* w1          = (const float*)d_in[12];
    const float* b1          = (const float*)d_in[13];
    const float* w2          = (const float*)d_in[14];
    const float* b2          = (const float*)d_in[15];
    const float* w_out       = (const float*)d_in[16];
    const float* b_out       = (const float*)d_in[17];

    const int Btot = in_sizes[0];
    const int totG = in_sizes[2];
    const int grid = (Btot + BT - 1) / BT;

    ncf_fused<<<grid, NTHREADS, 0, stream>>>(
        user_ids, movie_ids, genre_ids, offsets,
        user_mem_w, movie_mem_w,
        ue_gmf, me_gmf, ge_gmf,
        ue_mlp, me_mlp, ge_mlp,
        w1, b1, w2, b2, w_out, b_out,
        (float*)d_out, Btot, totG);
}

// Round 2
// 45.249 us; speedup vs baseline: 1.0615x; 1.0615x over previous
//
#include <hip/hip_runtime.h>

#define BT 64
#define NTHREADS 256

typedef __attribute__((ext_vector_type(8))) __bf16 bf16x8;
typedef __attribute__((ext_vector_type(4))) float f32x4;

__device__ __forceinline__ __bf16 f2bf(float f) { return (__bf16)f; }

// One-time per-launch: convert w1 (64x192) and w2 (96x64) f32 -> bf16 into ws.
__global__ void prep_weights(const float* __restrict__ w1, const float* __restrict__ w2,
                             __bf16* __restrict__ wbf) {
    const int i = blockIdx.x * 256 + threadIdx.x;
    if (i < 12288)       wbf[i] = f2bf(w1[i]);
    else if (i < 18432)  wbf[i] = f2bf(w2[i - 12288]);
}

__global__ __launch_bounds__(NTHREADS, 4)
void ncf_fused(const int* __restrict__ user_ids, const int* __restrict__ movie_ids,
               const int* __restrict__ genre_ids, const int* __restrict__ offsets,
               const float* __restrict__ user_mem_w, const float* __restrict__ movie_mem_w,
               const float* __restrict__ ue_gmf, const float* __restrict__ me_gmf,
               const float* __restrict__ ge_gmf,
               const float* __restrict__ ue_mlp, const float* __restrict__ me_mlp,
               const float* __restrict__ ge_mlp,
               const float* __restrict__ b1, const float* __restrict__ b2,
               const float* __restrict__ w_out, const float* __restrict__ b_out,
               const __bf16* __restrict__ wbf,
               float* __restrict__ out, int Btot, int totG)
{
    __shared__ __bf16 Hs[BT * 72];   // H [64][64+8] bf16

    const int tid  = threadIdx.x;
    const int lane = tid & 63;
    const int wid  = tid >> 6;       // 4 waves, 16 elements each
    const int lr   = lane & 15;      // element-row within wave tile
    const int lg   = lane >> 4;      // k-chunk / d-chunk group (0..3)
    const int e0   = blockIdx.x * BT;

    const int erow = wid * 16 + lr;              // element row in block (0..63)
    const int gidx = min(e0 + erow, Btot - 1);
    const int u    = user_ids[gidx];
    const int mv   = movie_ids[gidx];
    const int gs   = offsets[gidx];
    const int gend = (gidx + 1 < Btot) ? offsets[gidx + 1] : totG;
    const int cnt  = gend - gs;
    const float inv = 1.0f / (float)(cnt > 0 ? cnt : 1);

    // ---------- single genre pass: accumulate all 4 partial sums ----------
    // gm0/gm1: ge_mlp[g][lg*8 .. lg*8+7]   (A-frag kt=5 chunk)
    // gg0:     ge_gmf[g][4*lg .. 4*lg+3]   (GMF chunk j=4)
    // gg1:     ge_gmf[g][16+4*lg .. +3]    (GMF chunk j=5)
    f32x4 gm0 = {0.f,0.f,0.f,0.f}, gm1 = {0.f,0.f,0.f,0.f};
    f32x4 gg0 = {0.f,0.f,0.f,0.f}, gg1 = {0.f,0.f,0.f,0.f};
    for (int i = gs; i < gend; ++i) {
        const int g = genre_ids[i];
        const f32x4* pm = (const f32x4*)(ge_mlp + (size_t)g * 32 + lg * 8);
        gm0 += pm[0];
        gm1 += pm[1];
        const float* pg = ge_gmf + (size_t)g * 32 + 4 * lg;
        gg0 += *(const f32x4*)pg;
        gg1 += *(const f32x4*)(pg + 16);
    }

    // ---------- A-fragments directly into registers ----------
    // lane (lr,lg) holds X[row=erow][k = kt*32 + lg*8 .. +7], kt = 0..5
    bf16x8 fr[6];
    {
        const float* up = ue_mlp + (size_t)u * 96 + lg * 8;   // kt 0..2: k = kt*32+lg*8 < 96
        const float* mp = me_mlp + (size_t)mv * 64 + lg * 8;  // kt 3..4: k-96
        #pragma unroll
        for (int kt = 0; kt < 3; ++kt) {
            f32x4 a = *(const f32x4*)(up + kt * 32);
            f32x4 b = *(const f32x4*)(up + kt * 32 + 4);
            bf16x8 t;
            t[0]=f2bf(a[0]); t[1]=f2bf(a[1]); t[2]=f2bf(a[2]); t[3]=f2bf(a[3]);
            t[4]=f2bf(b[0]); t[5]=f2bf(b[1]); t[6]=f2bf(b[2]); t[7]=f2bf(b[3]);
            fr[kt] = t;
        }
        #pragma unroll
        for (int kt = 0; kt < 2; ++kt) {
            f32x4 a = *(const f32x4*)(mp + kt * 32);
            f32x4 b = *(const f32x4*)(mp + kt * 32 + 4);
            bf16x8 t;
            t[0]=f2bf(a[0]); t[1]=f2bf(a[1]); t[2]=f2bf(a[2]); t[3]=f2bf(a[3]);
            t[4]=f2bf(b[0]); t[5]=f2bf(b[1]); t[6]=f2bf(b[2]); t[7]=f2bf(b[3]);
            fr[3 + kt] = t;
        }
        bf16x8 t;
        t[0]=f2bf(gm0[0]*inv); t[1]=f2bf(gm0[1]*inv); t[2]=f2bf(gm0[2]*inv); t[3]=f2bf(gm0[3]*inv);
        t[4]=f2bf(gm1[0]*inv); t[5]=f2bf(gm1[1]*inv); t[6]=f2bf(gm1[2]*inv); t[7]=f2bf(gm1[3]*inv);
        fr[5] = t;
    }

    // ---------- GMF dot (f32 exact) ----------
    // chunk map: j=0..3 -> d = 4*lg + 16*j (movie part, d<64); j=4,5 -> d = 64 + 4*lg + 16*(j-4)
    float pval;
    {
        float s = 0.f;
        #pragma unroll
        for (int j = 0; j < 4; ++j) {
            const int d = 4 * lg + 16 * j;
            f32x4 ug = *(const f32x4*)(ue_gmf + (size_t)u * 96 + d);
            f32x4 mg = *(const f32x4*)(me_gmf + (size_t)mv * 64 + d);
            f32x4 wo = *(const f32x4*)(w_out + d);
            s += ug[0]*mg[0]*wo[0] + ug[1]*mg[1]*wo[1] + ug[2]*mg[2]*wo[2] + ug[3]*mg[3]*wo[3];
        }
        {
            const int d = 64 + 4 * lg;
            f32x4 ug = *(const f32x4*)(ue_gmf + (size_t)u * 96 + d);
            f32x4 wo = *(const f32x4*)(w_out + d);
            s += ug[0]*gg0[0]*inv*wo[0] + ug[1]*gg0[1]*inv*wo[1] + ug[2]*gg0[2]*inv*wo[2] + ug[3]*gg0[3]*inv*wo[3];
        }
        {
            const int d = 80 + 4 * lg;
            f32x4 ug = *(const f32x4*)(ue_gmf + (size_t)u * 96 + d);
            f32x4 wo = *(const f32x4*)(w_out + d);
            s += ug[0]*gg1[0]*inv*wo[0] + ug[1]*gg1[1]*inv*wo[1] + ug[2]*gg1[2]*inv*wo[2] + ug[3]*gg1[3]*inv*wo[3];
        }
        if (lg == 0)
            s += user_mem_w[u] + movie_mem_w[mv] + b_out[0];
        // butterfly across the 4 lanes sharing lr (lg dimension = lane bits 4,5)
        s += __shfl_xor(s, 16);
        s += __shfl_xor(s, 32);
        pval = s;   // every lane: full partial for element row lr
    }

    // ---------- GEMM1: X[64x192] @ W1^T -> H [64x64] ----------
    const __bf16* w1bf = wbf;
    f32x4 acc1[4] = {};
    #pragma unroll
    for (int kt = 0; kt < 6; ++kt) {
        #pragma unroll
        for (int nt = 0; nt < 4; ++nt) {
            bf16x8 bw = *(const bf16x8*)(w1bf + (size_t)(nt * 16 + lr) * 192 + kt * 32 + lg * 8);
            acc1[nt] = __builtin_amdgcn_mfma_f32_16x16x32_bf16(fr[kt], bw, acc1[nt], 0, 0, 0);
        }
    }
    // bias + relu -> Hs   (D layout: row = lg*4+r, col = lr)
    #pragma unroll
    for (int nt = 0; nt < 4; ++nt) {
        const float bv = b1[nt * 16 + lr];
        #pragma unroll
        for (int r = 0; r < 4; ++r) {
            float v = acc1[nt][r] + bv;
            v = v > 0.f ? v : 0.f;
            Hs[(wid * 16 + lg * 4 + r) * 72 + nt * 16 + lr] = f2bf(v);
        }
    }
    __syncthreads();

    // ---------- GEMM2: H[64x64] @ W2^T -> [64x96], fused epilogue ----------
    const __bf16* w2bf = wbf + 12288;
    f32x4 acc2[6] = {};
    #pragma unroll
    for (int kt = 0; kt < 2; ++kt) {
        bf16x8 av = *(const bf16x8*)&Hs[(wid * 16 + lr) * 72 + kt * 32 + lg * 8];
        #pragma unroll
        for (int nt = 0; nt < 6; ++nt) {
            bf16x8 bw = *(const bf16x8*)(w2bf + (size_t)(nt * 16 + lr) * 64 + kt * 32 + lg * 8);
            acc2[nt] = __builtin_amdgcn_mfma_f32_16x16x32_bf16(av, bw, acc2[nt], 0, 0, 0);
        }
    }

    float s0 = 0.f, s1 = 0.f, s2 = 0.f, s3 = 0.f;
    #pragma unroll
    for (int nt = 0; nt < 6; ++nt) {
        const int col = nt * 16 + lr;
        const float b2v = b2[col];
        const float wo  = w_out[96 + col];
        float v;
        v = acc2[nt][0] + b2v; v = v > 0.f ? v : 0.f; s0 += v * wo;
        v = acc2[nt][1] + b2v; v = v > 0.f ? v : 0.f; s1 += v * wo;
        v = acc2[nt][2] + b2v; v = v > 0.f ? v : 0.f; s2 += v * wo;
        v = acc2[nt][3] + b2v; v = v > 0.f ? v : 0.f; s3 += v * wo;
    }
    #pragma unroll
    for (int mask = 1; mask <= 8; mask <<= 1) {
        s0 += __shfl_xor(s0, mask);
        s1 += __shfl_xor(s1, mask);
        s2 += __shfl_xor(s2, mask);
        s3 += __shfl_xor(s3, mask);
    }
    // partial for rows lg*4+r lives on lane (lr = lg*4+r, lg'=0) == lane index lg*4+r
    const float p0 = __shfl(pval, lg * 4 + 0);
    const float p1 = __shfl(pval, lg * 4 + 1);
    const float p2 = __shfl(pval, lg * 4 + 2);
    const float p3 = __shfl(pval, lg * 4 + 3);

    if (lr == 0) {
        const int rowb = e0 + wid * 16 + lg * 4;
        if (rowb + 0 < Btot) out[rowb + 0] = p0 + s0;
        if (rowb + 1 < Btot) out[rowb + 1] = p1 + s1;
        if (rowb + 2 < Btot) out[rowb + 2] = p2 + s2;
        if (rowb + 3 < Btot) out[rowb + 3] = p3 + s3;
    }
}

extern "C" void kernel_launch(void* const* d_in, const int* in_sizes, int n_in,
                              void* d_out, int out_size, void* d_ws, size_t ws_size,
                              hipStream_t stream) {
    const int*   user_ids    = (const int*)d_in[0];
    const int*   movie_ids   = (const int*)d_in[1];
    const int*   genre_ids   = (const int*)d_in[2];
    const int*   offsets     = (const int*)d_in[3];
    const float* user_mem_w  = (const float*)d_in[4];
    const float* movie_mem_w = (const float*)d_in[5];
    const float* ue_gmf      = (const float*)d_in[6];
    const float* me_gmf      = (const float*)d_in[7];
    const float* ge_gmf      = (const float*)d_in[8];
    const float* ue_mlp      = (const float*)d_in[9];
    const float* me_mlp      = (const float*)d_in[10];
    const float* ge_mlp      = (const float*)d_in[11];
    const float* w1          = (const float*)d_in[12];
    const float* b1          = (const float*)d_in[13];
    const float* w2          = (const float*)d_in[14];
    const float* b2          = (const float*)d_in[15];
    const float* w_out       = (const float*)d_in[16];
    const float* b_out       = (const float*)d_in[17];

    const int Btot = in_sizes[0];
    const int totG = in_sizes[2];

    __bf16* wbf = (__bf16*)d_ws;
    prep_weights<<<72, 256, 0, stream>>>(w1, w2, wbf);

    const int grid = (Btot + BT - 1) / BT;
    ncf_fused<<<grid, NTHREADS, 0, stream>>>(
        user_ids, movie_ids, genre_ids, offsets,
        user_mem_w, movie_mem_w,
        ue_gmf, me_gmf, ge_gmf,
        ue_mlp, me_mlp, ge_mlp,
        b1, b2, w_out, b_out,
        wbf, (float*)d_out, Btot, totG);
}